// Round 3
// baseline (1258.776 us; speedup 1.0000x reference)
//
#include <hip/hip_runtime.h>
#include <math.h>

#define DEV __device__ __forceinline__

typedef _Float16 f16;
typedef _Float16 f16x8 __attribute__((ext_vector_type(8)));
typedef _Float16 f16x4 __attribute__((ext_vector_type(4)));
typedef float f32x4 __attribute__((ext_vector_type(4)));

DEV void gload_lds16(const void* g, void* l) {
  __builtin_amdgcn_global_load_lds(
      (const __attribute__((address_space(1))) void*)g,
      (__attribute__((address_space(3))) void*)l, 16, 0, 0);
}

// ---------------------------------------------------------------------------
// Weight transpose + f32->f16 convert: src [R][C] f32 -> dst [C][R] f16
// grid (C/32, R/32), block (32,8)
__global__ void transpose_w(const float* __restrict__ src, f16* __restrict__ dst,
                            int R, int C) {
  __shared__ float tile[32][33];
  int c0 = blockIdx.x * 32, r0 = blockIdx.y * 32;
  int tx = threadIdx.x, ty = threadIdx.y;
#pragma unroll
  for (int j = 0; j < 32; j += 8)
    tile[ty + j][tx] = src[(size_t)(r0 + ty + j) * C + c0 + tx];
  __syncthreads();
#pragma unroll
  for (int j = 0; j < 32; j += 8)
    dst[(size_t)(c0 + ty + j) * R + r0 + tx] = (f16)tile[tx][ty + j];
}

// ---------------------------------------------------------------------------
// RoPE sin/cos table: tab[pos][0..127]=sin, [128..255]=cos. 2048 pos x 128 j
__global__ void rope_table_k(float* __restrict__ tab) {
  int idx = blockIdx.x * 256 + threadIdx.x;  // 1024 blocks -> 262144 = 2048*128
  int pos = idx >> 7, j = idx & 127;
  float ts = powf(10000.0f, (float)j * (1.0f / 128.0f));
  float ang = (float)pos / ts;
  tab[pos * 256 + j] = sinf(ang);
  tab[pos * 256 + 128 + j] = cosf(ang);
}

// ---------------------------------------------------------------------------
// h = rmsnorm(in, scale) -> f16. one block per row, D=2560
__global__ __launch_bounds__(256) void rmsnorm_f32_f16(
    const float* __restrict__ in, const float* __restrict__ scale,
    f16* __restrict__ out) {
  constexpr int D = 2560, N4 = D / 4;
  const int m = blockIdx.x, tid = threadIdx.x;
  const float* row = in + (size_t)m * D;
  float vals[12];
  float ss = 0.f;
#pragma unroll
  for (int it = 0; it < 3; ++it) {
    int c4 = tid + it * 256;
    if (c4 < N4) {
      float4 v = *(const float4*)(row + c4 * 4);
      vals[it * 4 + 0] = v.x; vals[it * 4 + 1] = v.y;
      vals[it * 4 + 2] = v.z; vals[it * 4 + 3] = v.w;
      ss += v.x * v.x + v.y * v.y + v.z * v.z + v.w * v.w;
    }
  }
#pragma unroll
  for (int off = 32; off; off >>= 1) ss += __shfl_xor(ss, off, 64);
  __shared__ float red[4];
  if ((tid & 63) == 0) red[tid >> 6] = ss;
  __syncthreads();
  float rs = rsqrtf((red[0] + red[1] + red[2] + red[3]) * (1.0f / D) + 1e-6f);
#pragma unroll
  for (int it = 0; it < 3; ++it) {
    int c4 = tid + it * 256;
    if (c4 < N4) {
      float4 sc = *(const float4*)(scale + c4 * 4);
      f16x4 o;
      o[0] = (f16)(vals[it * 4 + 0] * rs * sc.x);
      o[1] = (f16)(vals[it * 4 + 1] * rs * sc.y);
      o[2] = (f16)(vals[it * 4 + 2] * rs * sc.z);
      o[3] = (f16)(vals[it * 4 + 3] * rs * sc.w);
      *(f16x4*)(out + (size_t)m * D + c4 * 4) = o;
    }
  }
}

// out = x + rmsnorm(y, scale); safe when out aliases x (per-thread RMW)
__global__ __launch_bounds__(256) void residual_rmsnorm(
    const float* x, const f16* __restrict__ y,
    const float* __restrict__ scale, float* out) {
  constexpr int D = 2560, N4 = D / 4;
  const int m = blockIdx.x, tid = threadIdx.x;
  const f16* yr = y + (size_t)m * D;
  float yv[12];
  float ss = 0.f;
#pragma unroll
  for (int it = 0; it < 3; ++it) {
    int c4 = tid + it * 256;
    if (c4 < N4) {
      f16x4 u = *(const f16x4*)(yr + c4 * 4);
      float a = (float)u[0], b = (float)u[1], c = (float)u[2], d = (float)u[3];
      yv[it * 4 + 0] = a; yv[it * 4 + 1] = b; yv[it * 4 + 2] = c; yv[it * 4 + 3] = d;
      ss += a * a + b * b + c * c + d * d;
    }
  }
#pragma unroll
  for (int off = 32; off; off >>= 1) ss += __shfl_xor(ss, off, 64);
  __shared__ float red[4];
  if ((tid & 63) == 0) red[tid >> 6] = ss;
  __syncthreads();
  float rs = rsqrtf((red[0] + red[1] + red[2] + red[3]) * (1.0f / D) + 1e-6f);
#pragma unroll
  for (int it = 0; it < 3; ++it) {
    int c4 = tid + it * 256;
    if (c4 < N4) {
      float4 xv = *(const float4*)(x + (size_t)m * D + c4 * 4);
      float4 sc = *(const float4*)(scale + c4 * 4);
      float4 o;
      o.x = xv.x + yv[it * 4 + 0] * rs * sc.x;
      o.y = xv.y + yv[it * 4 + 1] * rs * sc.y;
      o.z = xv.z + yv[it * 4 + 2] * rs * sc.z;
      o.w = xv.w + yv[it * 4 + 3] * rs * sc.w;
      *(float4*)(out + (size_t)m * D + c4 * 4) = o;
    }
  }
}

// ---------------------------------------------------------------------------
// Per-head rmsnorm (+RoPE for q,k) on qkv [4096][4096] f16.
// vectors: 0-7 q heads, 8-11 k heads, 12-15 v heads. one block per token.
__global__ __launch_bounds__(256) void norm_rope_k(
    const f16* __restrict__ qkv, const int* __restrict__ positions,
    const float* __restrict__ q_scale, const float* __restrict__ k_scale,
    const float* __restrict__ tab,
    f16* __restrict__ q_g, f16* __restrict__ k_g, f16* __restrict__ v_n) {
  const int m = blockIdx.x;
  const int tid = threadIdx.x, w = tid >> 6, l = tid & 63;
  const int pos = positions[m];
  const float* srow = tab + (size_t)pos * 256;
  const int c0 = l * 4;
  for (int vi = w; vi < 16; vi += 4) {
    f16x4 u = *(const f16x4*)(qkv + (size_t)m * 4096 + vi * 256 + c0);
    float x0 = (float)u[0], x1 = (float)u[1], x2 = (float)u[2], x3 = (float)u[3];
    float ss = x0 * x0 + x1 * x1 + x2 * x2 + x3 * x3;
#pragma unroll
    for (int off = 32; off; off >>= 1) ss += __shfl_xor(ss, off, 64);
    float rs = rsqrtf(ss * (1.0f / 256.0f) + 1e-6f);
    if (vi < 12) {
      const float* sc = (vi < 8) ? q_scale : k_scale;
      float4 s4 = *(const float4*)(sc + c0);
      float n0 = x0 * rs * s4.x, n1 = x1 * rs * s4.y;
      float n2 = x2 * rs * s4.z, n3 = x3 * rs * s4.w;
      float p0 = __shfl_xor(n0, 32, 64), p1 = __shfl_xor(n1, 32, 64);
      float p2 = __shfl_xor(n2, 32, 64), p3 = __shfl_xor(n3, 32, 64);
      int j0 = c0 & 127;
      float4 sn = *(const float4*)(srow + j0);
      float4 cs = *(const float4*)(srow + 128 + j0);
      float sgn = (l < 32) ? -1.0f : 1.0f;
      f16x4 o;
      o[0] = (f16)(n0 * cs.x + sgn * p0 * sn.x);
      o[1] = (f16)(n1 * cs.y + sgn * p1 * sn.y);
      o[2] = (f16)(n2 * cs.z + sgn * p2 * sn.z);
      o[3] = (f16)(n3 * cs.w + sgn * p3 * sn.w);
      if (vi < 8) *(f16x4*)(q_g + (size_t)m * 2048 + vi * 256 + c0) = o;
      else        *(f16x4*)(k_g + (size_t)m * 1024 + (vi - 8) * 256 + c0) = o;
    } else {
      f16x4 o;
      o[0] = (f16)(x0 * rs); o[1] = (f16)(x1 * rs);
      o[2] = (f16)(x2 * rs); o[3] = (f16)(x3 * rs);
      *(f16x4*)(v_n + (size_t)m * 1024 + (vi - 12) * 256 + c0) = o;
    }
  }
}

// v_n [4096][1024] -> vt [B*KV=8][256][2048] (per-(b,kv) transposed)
__global__ void transpose_v_k(const f16* __restrict__ v_n, f16* __restrict__ vt) {
  __shared__ f16 tile[32][33];
  int bkv = blockIdx.z;
  int b = bkv >> 2, kv = bkv & 3;
  int t0 = blockIdx.x * 32, d0 = blockIdx.y * 32;
  int tx = threadIdx.x, ty = threadIdx.y;
#pragma unroll
  for (int j = 0; j < 32; j += 8)
    tile[ty + j][tx] =
        v_n[(size_t)(b * 2048 + t0 + ty + j) * 1024 + kv * 256 + d0 + tx];
  __syncthreads();
#pragma unroll
  for (int j = 0; j < 32; j += 8)
    vt[((size_t)bkv * 256 + d0 + ty + j) * 2048 + t0 + tx] = tile[tx][ty + j];
}

// ---------------------------------------------------------------------------
// 256x256 GEMM, 1-barrier-per-K-tile pipelined schedule.
// A [M][K] f16, BT [N][K] f16, C [M][N] f16. 512 threads = 8 waves (2Mx4N),
// BK=64, full double-buffer (128KB LDS), XOR-swizzled via pre-swizzled source.
// Per tile: issue ALL 24 frag ds_reads + all 8 stage loads at tile top; the
// compiler's fine-grained lgkm waits let MFMA cluster 1 start while later
// reads drain underneath (cross-pipe overlap within each wave). One
// [vmcnt(0); s_barrier] per tile, issued >=2 MFMA clusters after the last
// stage -> wait is pre-covered.
// EPI: 0=store, 1=gelu, 2=mul by aux[idx], 3=fused gate+up: B-panel rows
// 0-127 from BT (gate^T, 128 rows/block), 128-255 from aux (up^T); epilogue
// exchanges gelu(gate) via LDS and stores gelu(g)*u to C (width N, 128
// cols/block at bn*128).
// Requires K%64==0, M%256==0, grid (.,M/256), nwg%8==0.
template <int EPI>
__global__ __launch_bounds__(512, 2) void gemm256(
    const f16* __restrict__ A, const f16* __restrict__ BT,
    f16* __restrict__ C, const f16* __restrict__ aux, int M, int N, int K) {
  extern __shared__ __align__(16) f16 lds[];  // 131072 B
  const int tid = threadIdx.x;
  const int w = tid >> 6, l = tid & 63;
  const int l15 = l & 15, lk = l >> 4;
  const int wm = w >> 2, wn = w & 3;  // 2 x 4 wave grid

  // bijective XCD swizzle (all call-site grids have nwg % 8 == 0)
  const int gx = gridDim.x;
  const int nwg = gx * gridDim.y;
  const int orig = blockIdx.y * gx + blockIdx.x;
  const int swz = (orig & 7) * (nwg >> 3) + (orig >> 3);
  const int bn = swz % gx, bm = swz / gx;

  const int NT = K >> 6;

  // staging: thread writes 16B chunks at rows srow, srow+128 of the panel.
  // source col pre-swizzled so linear global_load_lds + swizzled ds_read agree.
  const int srow = tid >> 2;
  const int sg = (tid & 3) ^ ((srow >> 1) & 3);
  const f16* pA1 = A + (size_t)(bm * 256 + srow) * K + sg * 8;
  const f16* pA2 = pA1 + (size_t)128 * K;
  const f16* pB1;
  const f16* pB2;
  if constexpr (EPI == 3) {
    pB1 = BT + (size_t)(bn * 128 + srow) * K + sg * 8;
    pB2 = aux + (size_t)(bn * 128 + srow) * K + sg * 8;
  } else {
    pB1 = BT + (size_t)(bn * 256 + srow) * K + sg * 8;
    pB2 = pB1 + (size_t)128 * K;
  }

  // stage all 4 units (A-kh0, B-kh0, A-kh1, B-kh1) of tile kt into buffer buf
  auto stage4 = [&](int buf, int kt) {
    const int kb = kt * 64;
    f16* base = lds + (buf << 2) * 8192 + tid * 8;
#pragma unroll
    for (int kh = 0; kh < 2; ++kh) {
      f16* dA = base + (kh << 1) * 8192;
      gload_lds16(pA1 + kb + kh * 32, dA);
      gload_lds16(pA2 + kb + kh * 32, dA + 4096);
      f16* dB = base + ((kh << 1) + 1) * 8192;
      gload_lds16(pB1 + kb + kh * 32, dB);
      gload_lds16(pB2 + kb + kh * 32, dB + 4096);
    }
  };

  // frag read offsets: row*32 elts + swizzled 16B slot (constant per thread)
  const int fcol = (lk ^ ((l15 >> 1) & 3)) << 3;
  const int aoff = (wm * 128 + l15) * 32 + fcol;          // A unit base + mi*512
  const int boff = 8192 + (wn * 64 + l15) * 32 + fcol;    // B unit base + ni*512

  f32x4 acc[8][4] = {};

  stage4(0, 0);
  asm volatile("s_waitcnt vmcnt(0)" ::: "memory");
  __builtin_amdgcn_s_barrier();
  asm volatile("" ::: "memory");

  for (int t = 0; t < NT; ++t) {
    const int buf = t & 1;
    const f16* lb0 = lds + buf * 32768;   // kh0 units
    const f16* lb1 = lb0 + 16384;         // kh1 units
    f16x8 a1[4], b1[4], a2[4], a3[4], b2[4], a4[4];
    // all frag reads for the whole tile, issued up front
#pragma unroll
    for (int i = 0; i < 4; ++i) a1[i] = *(const f16x8*)(lb0 + aoff + i * 512);
#pragma unroll
    for (int i = 0; i < 4; ++i) b1[i] = *(const f16x8*)(lb0 + boff + i * 512);
#pragma unroll
    for (int i = 0; i < 4; ++i) a2[i] = *(const f16x8*)(lb0 + aoff + (4 + i) * 512);
    if (t + 1 < NT) stage4(buf ^ 1, t + 1);
#pragma unroll
    for (int i = 0; i < 4; ++i) a3[i] = *(const f16x8*)(lb1 + aoff + i * 512);
#pragma unroll
    for (int i = 0; i < 4; ++i) b2[i] = *(const f16x8*)(lb1 + boff + i * 512);
#pragma unroll
    for (int i = 0; i < 4; ++i) a4[i] = *(const f16x8*)(lb1 + aoff + (4 + i) * 512);
    __builtin_amdgcn_s_setprio(1);
#pragma unroll
    for (int mi = 0; mi < 4; ++mi)
#pragma unroll
      for (int ni = 0; ni < 4; ++ni)
        acc[mi][ni] = __builtin_amdgcn_mfma_f32_16x16x32_f16(a1[mi], b1[ni], acc[mi][ni], 0, 0, 0);
#pragma unroll
    for (int mi = 0; mi < 4; ++mi)
#pragma unroll
      for (int ni = 0; ni < 4; ++ni)
        acc[4 + mi][ni] = __builtin_amdgcn_mfma_f32_16x16x32_f16(a2[mi], b1[ni], acc[4 + mi][ni], 0, 0, 0);
#pragma unroll
    for (int mi = 0; mi < 4; ++mi)
#pragma unroll
      for (int ni = 0; ni < 4; ++ni)
        acc[mi][ni] = __builtin_amdgcn_mfma_f32_16x16x32_f16(a3[mi], b2[ni], acc[mi][ni], 0, 0, 0);
#pragma unroll
    for (int mi = 0; mi < 4; ++mi)
#pragma unroll
      for (int ni = 0; ni < 4; ++ni)
        acc[4 + mi][ni] = __builtin_amdgcn_mfma_f32_16x16x32_f16(a4[mi], b2[ni], acc[4 + mi][ni], 0, 0, 0);
    __builtin_amdgcn_s_setprio(0);
    if (t + 1 < NT) {
      // all 8 loads for tile t+1 were issued >=2 MFMA clusters ago -> free wait
      asm volatile("s_waitcnt vmcnt(0)" ::: "memory");
      __builtin_amdgcn_s_barrier();
      asm volatile("" ::: "memory");
    }
  }

  // epilogue: C/D map col=l15, row=lk*4+i (m89-verified)
  if constexpr (EPI == 3) {
    // gate waves (wn<2) write gelu(g) to LDS; up waves (wn>=2) read, mul, store
    __syncthreads();
    float* xls = (float*)lds;  // [256][128] f32 = 128 KB
    if (wn < 2) {
#pragma unroll
      for (int mi = 0; mi < 8; ++mi)
#pragma unroll
        for (int ni = 0; ni < 4; ++ni)
#pragma unroll
          for (int i = 0; i < 4; ++i) {
            int row = wm * 128 + mi * 16 + lk * 4 + i;
            int col = wn * 64 + ni * 16 + l15;
            float v = acc[mi][ni][i];
            v = 0.5f * v * (1.0f + erff(v * 0.70710678118654752f));
            xls[row * 128 + col] = v;
          }
    }
    __syncthreads();
    if (wn >= 2) {
#pragma unroll
      for (int mi = 0; mi < 8; ++mi)
#pragma unroll
        for (int ni = 0; ni < 4; ++ni)
#pragma unroll
          for (int i = 0; i < 4; ++i) {
            int row = wm * 128 + mi * 16 + lk * 4 + i;
            int colg = (wn - 2) * 64 + ni * 16 + l15;
            float g = xls[row * 128 + colg];
            float v = g * acc[mi][ni][i];
            C[(size_t)(bm * 256 + row) * N + bn * 128 + colg] = (f16)v;
          }
    }
  } else {
#pragma unroll
    for (int mi = 0; mi < 8; ++mi) {
#pragma unroll
      for (int ni = 0; ni < 4; ++ni) {
#pragma unroll
        for (int i = 0; i < 4; ++i) {
          int row = bm * 256 + wm * 128 + mi * 16 + lk * 4 + i;
          int col = bn * 256 + wn * 64 + ni * 16 + l15;
          size_t idx = (size_t)row * N + col;
          float v = acc[mi][ni][i];
          if constexpr (EPI == 1) {
            v = 0.5f * v * (1.0f + erff(v * 0.70710678118654752f));
          } else if constexpr (EPI == 2) {
            v *= (float)aux[idx];
          }
          C[idx] = (f16)v;
        }
      }
    }
  }
}

// ---------------------------------------------------------------------------
// Flash attention, sliding window 1024, GQA rep=2.
// grid (L/64, H, B), block 256 (4 waves, 16 q-rows each). KV tile = 32.
__global__ __launch_bounds__(256) void flash_attn_k(
    const f16* __restrict__ q_g, const f16* __restrict__ k_g,
    const f16* __restrict__ vt, f16* __restrict__ ctx) {
  constexpr int KP = 264, VP = 40, PP = 40;
  __shared__ f16 Ks[32 * KP];
  __shared__ f16 Vs[256 * VP];
  __shared__ f16 Ps[4][16 * PP];
  const int qt = blockIdx.x, h = blockIdx.y, b = blockIdx.z;
  const int tid = threadIdx.x, w = tid >> 6, l = tid & 63;
  const int l15 = l & 15, lk = l >> 4;
  const int kv = h >> 1;

  f16x8 aq[8];
  const int qrow = qt * 64 + w * 16 + l15;
  const f16* qp = q_g + (size_t)(b * 2048 + qrow) * 2048 + h * 256 + lk * 8;
#pragma unroll
  for (int kc = 0; kc < 8; ++kc) aq[kc] = *(const f16x8*)(qp + kc * 32);

  f32x4 o[16] = {};
  float mrow[4] = {-1e30f, -1e30f, -1e30f, -1e30f};
  float lrow[4] = {0.f, 0.f, 0.f, 0.f};

  int kt_lo = 2 * qt - 32; if (kt_lo < 0) kt_lo = 0;
  const int kt_hi = 2 * qt + 1;
  const int iqb = qt * 64 + w * 16 + lk * 4;

  for (int kt = kt_lo; kt <= kt_hi; ++kt) {
    __syncthreads();
#pragma unroll
    for (int it = 0; it < 4; ++it) {
      int ch = tid + it * 256;
      int jl = ch >> 5, kcc = (ch & 31) * 8;
      *(f16x8*)&Ks[jl * KP + kcc] = *(const f16x8*)(
          k_g + (size_t)(b * 2048 + kt * 32 + jl) * 1024 + kv * 256 + kcc);
      int d = ch >> 2, tc = (ch & 3) * 8;
      *(f16x8*)&Vs[d * VP + tc] = *(const f16x8*)(
          vt + ((size_t)(b * 4 + kv) * 256 + d) * 2048 + kt * 32 + tc);
    }
    __syncthreads();
    // S = Q K^T  (16q x 32k per wave)
    f32x4 s[2] = {};
#pragma unroll
    for (int ct = 0; ct < 2; ++ct)
#pragma unroll
      for (int kc = 0; kc < 8; ++kc) {
        f16x8 bk = *(const f16x8*)&Ks[(ct * 16 + l15) * KP + kc * 32 + lk * 8];
        s[ct] = __builtin_amdgcn_mfma_f32_16x16x32_f16(aq[kc], bk, s[ct], 0, 0, 0);
      }
    // mask + online softmax
    float pm[4] = {-1e30f, -1e30f, -1e30f, -1e30f};
#pragma unroll
    for (int ct = 0; ct < 2; ++ct)
#pragma unroll
      for (int i = 0; i < 4; ++i) {
        int iq = iqb + i;
        int j = kt * 32 + ct * 16 + l15;
        bool valid = (j <= iq) && (j > iq - 1024);
        float sv = valid ? s[ct][i] : -1e30f;
        s[ct][i] = sv;
        pm[i] = fmaxf(pm[i], sv);
      }
#pragma unroll
    for (int i = 0; i < 4; ++i)
#pragma unroll
      for (int off = 1; off < 16; off <<= 1)
        pm[i] = fmaxf(pm[i], __shfl_xor(pm[i], off, 64));
    float corr[4], rsum[4];
#pragma unroll
    for (int i = 0; i < 4; ++i) {
      float mn = fmaxf(mrow[i], pm[i]);
      corr[i] = __expf(mrow[i] - mn);
      mrow[i] = mn;
      rsum[i] = 0.f;
    }
#pragma unroll
    for (int ct = 0; ct < 2; ++ct)
#pragma unroll
      for (int i = 0; i < 4; ++i) {
        float p = (s[ct][i] > -1e29f) ? __expf(s[ct][i] - mrow[i]) : 0.f;
        s[ct][i] = p;
        rsum[i] += p;
      }
#pragma unroll
    for (int i = 0; i < 4; ++i) {
#pragma unroll
      for (int off = 1; off < 16; off <<= 1) rsum[i] += __shfl_xor(rsum[i], off, 64);
      lrow[i] = lrow[i] * corr[i] + rsum[i];
    }
#pragma unroll
    for (int dt = 0; dt < 16; ++dt)
#pragma unroll
      for (int i = 0; i < 4; ++i) o[dt][i] *= corr[i];
    // P -> LDS (f16)
#pragma unroll
    for (int ct = 0; ct < 2; ++ct)
#pragma unroll
      for (int i = 0; i < 4; ++i)
        Ps[w][(lk * 4 + i) * PP + ct * 16 + l15] = (f16)s[ct][i];
    __syncthreads();
    // O += P V
    f16x8 pa = *(const f16x8*)&Ps[w][l15 * PP + lk * 8];
#pragma unroll
    for (int dt = 0; dt < 16; ++dt) {
      f16x8 bv = *(const f16x8*)&Vs[(dt * 16 + l15) * VP + lk * 8];
      o[dt] = __builtin_amdgcn_mfma_f32_16x16x32_f16(pa, bv, o[dt], 0, 0, 0);
    }
  }
  float inv[4];
#pragma unroll
  for (int i = 0; i < 4; ++i) inv[i] = 1.0f / lrow[i];
  f16* op = ctx + (size_t)(b * 2048 + qt * 64 + w * 16 + lk * 4) * 2048 + h * 256 + l15;
#pragma unroll
  for (int dt = 0; dt < 16; ++dt)
#pragma unroll
    for (int i = 0; i < 4; ++i)
      op[(size_t)i * 2048 + dt * 16] = (f16)(o[dt][i] * inv[i]);
}

// ---------------------------------------------------------------------------
extern "C" void kernel_launch(void* const* d_in, const int* in_sizes, int n_in,
                              void* d_out, int out_size, void* d_ws, size_t ws_size,
                              hipStream_t stream) {
  const float* x = (const float*)d_in[0];
  const int* positions = (const int*)d_in[1];
  const float* wq = (const float*)d_in[2];
  const float* wk = (const float*)d_in[3];
  const float* wv = (const float*)d_in[4];
  const float* wo = (const float*)d_in[5];
  const float* q_scale = (const float*)d_in[6];
  const float* k_scale = (const float*)d_in[7];
  const float* pre_attn = (const float*)d_in[8];
  const float* post_attn = (const float*)d_in[9];
  const float* pre_ffw = (const float*)d_in[10];
  const float* post_ffw = (const float*)d_in[11];
  const float* w_gate = (const float*)d_in[12];
  const float* w_up = (const float*)d_in[13];
  const float* w_down = (const float*)d_in[14];
  float* out = (float*)d_out;

  // one-time: allow 128KB dynamic LDS on the GEMM (attribute set, not a stream op)
  static bool s_attr = []() {
    hipFuncSetAttribute(reinterpret_cast<const void*>(&gemm256<0>),
                        hipFuncAttributeMaxDynamicSharedMemorySize, 131072);
    hipFuncSetAttribute(reinterpret_cast<const void*>(&gemm256<1>),
                        hipFuncAttributeMaxDynamicSharedMemorySize, 131072);
    hipFuncSetAttribute(reinterpret_cast<const void*>(&gemm256<2>),
                        hipFuncAttributeMaxDynamicSharedMemorySize, 131072);
    hipFuncSetAttribute(reinterpret_cast<const void*>(&gemm256<3>),
                        hipFuncAttributeMaxDynamicSharedMemorySize, 131072);
    return true;
  }();
  (void)s_attr;

  // ---- workspace layout ----
  const size_t WT_BIG   = (size_t)20480 * 2560 * 2;  // gate^T + up^T resident
  const size_t WT_SMALL = (size_t)10240 * 2560 * 2;
  const size_t TAB_B = (size_t)2048 * 256 * 4;
  const size_t H_B   = (size_t)4096 * 2560 * 2;
  const size_t ACT_B = (size_t)92280832;
  auto aln = [](size_t v) { return (v + 255) & ~(size_t)255; };
  const bool big = ws_size >= aln(WT_BIG) + aln(TAB_B) + aln(H_B) + aln(ACT_B);

  char* ws = (char*)d_ws;
  size_t off = 0;
  auto alloc = [&](size_t bytes) {
    char* p = ws + off;
    off += (bytes + 255) & ~(size_t)255;
    return p;
  };
  f16* wT    = (f16*)alloc(big ? WT_BIG : WT_SMALL);
  float* tab = (float*)alloc(TAB_B);
  f16* h     = (f16*)alloc(H_B);
  char* act  = alloc(ACT_B);
  // attention-phase overlays inside act:
  f16* qkv    = (f16*)(act);                                    // 33.5 MB
  f16* q_g    = (f16*)(act + (size_t)33554432);                 // 16.8 MB
  f16* k_g    = (f16*)(act + (size_t)33554432 + 16777216);      //  8.4 MB
  f16* v_n    = (f16*)(act + (size_t)33554432 + 16777216 + 8388608);
  f16* vtb    = (f16*)(act + (size_t)33554432 + 16777216 + 2 * 8388608);
  f16* ctx    = (f16*)(act + (size_t)33554432 + 16777216 + 3 * 8388608);
  f16* attn_o = (f16*)(act);            // reuse qkv slot (dead after norm_rope)
  // ffw-phase overlays:
  f16* gbuf = (f16*)(act);              // 83.9 MB spans whole act region
  f16* ffw  = h;                        // h dead after it's consumed as GEMM A
  f16* wuT  = wT + (size_t)10240 * 2560;  // big path only
  (void)in_sizes; (void)n_in; (void)out_size;

  dim3 tb(32, 8);
  rope_table_k<<<1024, 256, 0, stream>>>(tab);

  // ---- attention path ----
  rmsnorm_f32_f16<<<4096, 256, 0, stream>>>(x, pre_attn, h);
  // wq|wk|wv -> wT as [4096][2560] (q rows 0-2047, k 2048-3071, v 3072-4095)
  transpose_w<<<dim3(2048 / 32, 2560 / 32), tb, 0, stream>>>(wq, wT, 2560, 2048);
  transpose_w<<<dim3(1024 / 32, 2560 / 32), tb, 0, stream>>>(wk, wT + (size_t)2048 * 2560, 2560, 1024);
  transpose_w<<<dim3(1024 / 32, 2560 / 32), tb, 0, stream>>>(wv, wT + (size_t)3072 * 2560, 2560, 1024);
  gemm256<0><<<dim3(4096 / 256, 4096 / 256), 512, 131072, stream>>>(h, wT, qkv, nullptr, 4096, 4096, 2560);
  norm_rope_k<<<4096, 256, 0, stream>>>(qkv, positions, q_scale, k_scale, tab, q_g, k_g, v_n);
  transpose_v_k<<<dim3(2048 / 32, 256 / 32, 8), tb, 0, stream>>>(v_n, vtb);
  flash_attn_k<<<dim3(32, 8, 2), 256, 0, stream>>>(q_g, k_g, vtb, ctx);
  transpose_w<<<dim3(2560 / 32, 2048 / 32), tb, 0, stream>>>(wo, wT, 2048, 2560);
  gemm256<0><<<dim3(2560 / 256, 4096 / 256), 512, 131072, stream>>>(ctx, wT, attn_o, nullptr, 4096, 2560, 2048);
  residual_rmsnorm<<<4096, 256, 0, stream>>>(x, attn_o, post_attn, out);

  // ---- ffw path ----
  rmsnorm_f32_f16<<<4096, 256, 0, stream>>>(out, pre_ffw, h);
  if (big) {
    // fused gate+up: grid 80x16 = 1280 blocks = 5.0 x 256 CUs (no tail)
    transpose_w<<<dim3(10240 / 32, 2560 / 32), tb, 0, stream>>>(w_gate, wT, 2560, 10240);
    transpose_w<<<dim3(10240 / 32, 2560 / 32), tb, 0, stream>>>(w_up, wuT, 2560, 10240);
    gemm256<3><<<dim3(80, 16), 512, 131072, stream>>>(h, wT, gbuf, wuT, 4096, 10240, 2560);
  } else {
    transpose_w<<<dim3(10240 / 32, 2560 / 32), tb, 0, stream>>>(w_gate, wT, 2560, 10240);
    gemm256<1><<<dim3(10240 / 256, 4096 / 256), 512, 131072, stream>>>(h, wT, gbuf, nullptr, 4096, 10240, 2560);
    transpose_w<<<dim3(10240 / 32, 2560 / 32), tb, 0, stream>>>(w_up, wT, 2560, 10240);
    gemm256<2><<<dim3(10240 / 256, 4096 / 256), 512, 131072, stream>>>(h, wT, gbuf, gbuf, 4096, 10240, 2560);
  }
  transpose_w<<<dim3(2560 / 32, 10240 / 32), tb, 0, stream>>>(w_down, wT, 10240, 2560);
  gemm256<0><<<dim3(2560 / 256, 4096 / 256), 512, 131072, stream>>>(gbuf, wT, ffw, nullptr, 4096, 2560, 10240);
  residual_rmsnorm<<<4096, 256, 0, stream>>>(out, ffw, post_ffw, out);
}

// Round 4
// 1197.730 us; speedup vs baseline: 1.0510x; 1.0510x over previous
//
#include <hip/hip_runtime.h>
#include <math.h>

#define DEV __device__ __forceinline__

typedef _Float16 f16;
typedef _Float16 f16x8 __attribute__((ext_vector_type(8)));
typedef _Float16 f16x4 __attribute__((ext_vector_type(4)));
typedef float f32x4 __attribute__((ext_vector_type(4)));

DEV void gload_lds16(const void* g, void* l) {
  __builtin_amdgcn_global_load_lds(
      (const __attribute__((address_space(1))) void*)g,
      (__attribute__((address_space(3))) void*)l, 16, 0, 0);
}

// ---------------------------------------------------------------------------
// Weight transpose + f32->f16 convert: src [R][C] f32 -> dst [C][R] f16
// grid (C/32, R/32), block (32,8)
__global__ void transpose_w(const float* __restrict__ src, f16* __restrict__ dst,
                            int R, int C) {
  __shared__ float tile[32][33];
  int c0 = blockIdx.x * 32, r0 = blockIdx.y * 32;
  int tx = threadIdx.x, ty = threadIdx.y;
#pragma unroll
  for (int j = 0; j < 32; j += 8)
    tile[ty + j][tx] = src[(size_t)(r0 + ty + j) * C + c0 + tx];
  __syncthreads();
#pragma unroll
  for (int j = 0; j < 32; j += 8)
    dst[(size_t)(c0 + ty + j) * R + r0 + tx] = (f16)tile[tx][ty + j];
}

// ---------------------------------------------------------------------------
// RoPE sin/cos table: tab[pos][0..127]=sin, [128..255]=cos. 2048 pos x 128 j
__global__ void rope_table_k(float* __restrict__ tab) {
  int idx = blockIdx.x * 256 + threadIdx.x;  // 1024 blocks -> 262144 = 2048*128
  int pos = idx >> 7, j = idx & 127;
  float ts = powf(10000.0f, (float)j * (1.0f / 128.0f));
  float ang = (float)pos / ts;
  tab[pos * 256 + j] = sinf(ang);
  tab[pos * 256 + 128 + j] = cosf(ang);
}

// ---------------------------------------------------------------------------
// h = rmsnorm(in, scale) -> f16. one block per row, D=2560
__global__ __launch_bounds__(256) void rmsnorm_f32_f16(
    const float* __restrict__ in, const float* __restrict__ scale,
    f16* __restrict__ out) {
  constexpr int D = 2560, N4 = D / 4;
  const int m = blockIdx.x, tid = threadIdx.x;
  const float* row = in + (size_t)m * D;
  float vals[12];
  float ss = 0.f;
#pragma unroll
  for (int it = 0; it < 3; ++it) {
    int c4 = tid + it * 256;
    if (c4 < N4) {
      float4 v = *(const float4*)(row + c4 * 4);
      vals[it * 4 + 0] = v.x; vals[it * 4 + 1] = v.y;
      vals[it * 4 + 2] = v.z; vals[it * 4 + 3] = v.w;
      ss += v.x * v.x + v.y * v.y + v.z * v.z + v.w * v.w;
    }
  }
#pragma unroll
  for (int off = 32; off; off >>= 1) ss += __shfl_xor(ss, off, 64);
  __shared__ float red[4];
  if ((tid & 63) == 0) red[tid >> 6] = ss;
  __syncthreads();
  float rs = rsqrtf((red[0] + red[1] + red[2] + red[3]) * (1.0f / D) + 1e-6f);
#pragma unroll
  for (int it = 0; it < 3; ++it) {
    int c4 = tid + it * 256;
    if (c4 < N4) {
      float4 sc = *(const float4*)(scale + c4 * 4);
      f16x4 o;
      o[0] = (f16)(vals[it * 4 + 0] * rs * sc.x);
      o[1] = (f16)(vals[it * 4 + 1] * rs * sc.y);
      o[2] = (f16)(vals[it * 4 + 2] * rs * sc.z);
      o[3] = (f16)(vals[it * 4 + 3] * rs * sc.w);
      *(f16x4*)(out + (size_t)m * D + c4 * 4) = o;
    }
  }
}

// out = x + rmsnorm(y, scale); safe when out aliases x (per-thread RMW)
__global__ __launch_bounds__(256) void residual_rmsnorm(
    const float* x, const f16* __restrict__ y,
    const float* __restrict__ scale, float* out) {
  constexpr int D = 2560, N4 = D / 4;
  const int m = blockIdx.x, tid = threadIdx.x;
  const f16* yr = y + (size_t)m * D;
  float yv[12];
  float ss = 0.f;
#pragma unroll
  for (int it = 0; it < 3; ++it) {
    int c4 = tid + it * 256;
    if (c4 < N4) {
      f16x4 u = *(const f16x4*)(yr + c4 * 4);
      float a = (float)u[0], b = (float)u[1], c = (float)u[2], d = (float)u[3];
      yv[it * 4 + 0] = a; yv[it * 4 + 1] = b; yv[it * 4 + 2] = c; yv[it * 4 + 3] = d;
      ss += a * a + b * b + c * c + d * d;
    }
  }
#pragma unroll
  for (int off = 32; off; off >>= 1) ss += __shfl_xor(ss, off, 64);
  __shared__ float red[4];
  if ((tid & 63) == 0) red[tid >> 6] = ss;
  __syncthreads();
  float rs = rsqrtf((red[0] + red[1] + red[2] + red[3]) * (1.0f / D) + 1e-6f);
#pragma unroll
  for (int it = 0; it < 3; ++it) {
    int c4 = tid + it * 256;
    if (c4 < N4) {
      float4 xv = *(const float4*)(x + (size_t)m * D + c4 * 4);
      float4 sc = *(const float4*)(scale + c4 * 4);
      float4 o;
      o.x = xv.x + yv[it * 4 + 0] * rs * sc.x;
      o.y = xv.y + yv[it * 4 + 1] * rs * sc.y;
      o.z = xv.z + yv[it * 4 + 2] * rs * sc.z;
      o.w = xv.w + yv[it * 4 + 3] * rs * sc.w;
      *(float4*)(out + (size_t)m * D + c4 * 4) = o;
    }
  }
}

// ---------------------------------------------------------------------------
// Per-head rmsnorm (+RoPE for q,k) on qkv [4096][4096] f16.
// vectors: 0-7 q heads, 8-11 k heads, 12-15 v heads. one block per token.
__global__ __launch_bounds__(256) void norm_rope_k(
    const f16* __restrict__ qkv, const int* __restrict__ positions,
    const float* __restrict__ q_scale, const float* __restrict__ k_scale,
    const float* __restrict__ tab,
    f16* __restrict__ q_g, f16* __restrict__ k_g, f16* __restrict__ v_n) {
  const int m = blockIdx.x;
  const int tid = threadIdx.x, w = tid >> 6, l = tid & 63;
  const int pos = positions[m];
  const float* srow = tab + (size_t)pos * 256;
  const int c0 = l * 4;
  for (int vi = w; vi < 16; vi += 4) {
    f16x4 u = *(const f16x4*)(qkv + (size_t)m * 4096 + vi * 256 + c0);
    float x0 = (float)u[0], x1 = (float)u[1], x2 = (float)u[2], x3 = (float)u[3];
    float ss = x0 * x0 + x1 * x1 + x2 * x2 + x3 * x3;
#pragma unroll
    for (int off = 32; off; off >>= 1) ss += __shfl_xor(ss, off, 64);
    float rs = rsqrtf(ss * (1.0f / 256.0f) + 1e-6f);
    if (vi < 12) {
      const float* sc = (vi < 8) ? q_scale : k_scale;
      float4 s4 = *(const float4*)(sc + c0);
      float n0 = x0 * rs * s4.x, n1 = x1 * rs * s4.y;
      float n2 = x2 * rs * s4.z, n3 = x3 * rs * s4.w;
      float p0 = __shfl_xor(n0, 32, 64), p1 = __shfl_xor(n1, 32, 64);
      float p2 = __shfl_xor(n2, 32, 64), p3 = __shfl_xor(n3, 32, 64);
      int j0 = c0 & 127;
      float4 sn = *(const float4*)(srow + j0);
      float4 cs = *(const float4*)(srow + 128 + j0);
      float sgn = (l < 32) ? -1.0f : 1.0f;
      f16x4 o;
      o[0] = (f16)(n0 * cs.x + sgn * p0 * sn.x);
      o[1] = (f16)(n1 * cs.y + sgn * p1 * sn.y);
      o[2] = (f16)(n2 * cs.z + sgn * p2 * sn.z);
      o[3] = (f16)(n3 * cs.w + sgn * p3 * sn.w);
      if (vi < 8) *(f16x4*)(q_g + (size_t)m * 2048 + vi * 256 + c0) = o;
      else        *(f16x4*)(k_g + (size_t)m * 1024 + (vi - 8) * 256 + c0) = o;
    } else {
      f16x4 o;
      o[0] = (f16)(x0 * rs); o[1] = (f16)(x1 * rs);
      o[2] = (f16)(x2 * rs); o[3] = (f16)(x3 * rs);
      *(f16x4*)(v_n + (size_t)m * 1024 + (vi - 12) * 256 + c0) = o;
    }
  }
}

// v_n [4096][1024] -> vt [B*KV=8][256][2048] (per-(b,kv) transposed)
__global__ void transpose_v_k(const f16* __restrict__ v_n, f16* __restrict__ vt) {
  __shared__ f16 tile[32][33];
  int bkv = blockIdx.z;
  int b = bkv >> 2, kv = bkv & 3;
  int t0 = blockIdx.x * 32, d0 = blockIdx.y * 32;
  int tx = threadIdx.x, ty = threadIdx.y;
#pragma unroll
  for (int j = 0; j < 32; j += 8)
    tile[ty + j][tx] =
        v_n[(size_t)(b * 2048 + t0 + ty + j) * 1024 + kv * 256 + d0 + tx];
  __syncthreads();
#pragma unroll
  for (int j = 0; j < 32; j += 8)
    vt[((size_t)bkv * 256 + d0 + ty + j) * 2048 + t0 + tx] = tile[tx][ty + j];
}

// ---------------------------------------------------------------------------
// 256x256 GEMM, round-2 schedule (best measured): 2 barriers per K-tile,
// counted vmcnt(6)/(4)/(0), per-pair [12 ds_reads; stage; MFMA x16; stage;
// MFMA x16]. A [M][K] f16, BT [N][K] f16, C [M][N] f16. 512 threads = 8
// waves (2Mx4N), BK=64 staged as 4x 16KB units, double-buffered (128KB LDS),
// XOR-swizzled via pre-swizzled global source.
// EPI: 0=store, 1=gelu(exact), 2=mul by aux[idx] (in-place allowed),
// 3=fused gate+up: B-panel rows 0-127 from BT (gate^T), rows 128-255 from
// aux (up^T); epilogue exchanges gelu(gate) via padded f16 LDS and stores
// gelu(g)*u to C cols [bn*128, bn*128+128).
// Requires K%64==0, M%256==0, grid (., M/256), nwg%8==0.
template <int EPI>
__global__ __launch_bounds__(512, 2) void gemm256(
    const f16* __restrict__ A, const f16* __restrict__ BT,
    f16* __restrict__ C, const f16* __restrict__ aux, int M, int N, int K) {
  extern __shared__ __align__(16) f16 lds[];  // 131072 B
  const int tid = threadIdx.x;
  const int w = tid >> 6, l = tid & 63;
  const int l15 = l & 15, lk = l >> 4;
  const int wm = w >> 2, wn = w & 3;  // 2 x 4 wave grid

  // bijective XCD swizzle (all call-site grids have nwg % 8 == 0)
  const int gx = gridDim.x;
  const int nwg = gx * gridDim.y;
  const int orig = blockIdx.y * gx + blockIdx.x;
  const int swz = (orig & 7) * (nwg >> 3) + (orig >> 3);
  const int bn = swz % gx, bm = swz / gx;

  const int NT = K >> 6;

  // staging: thread writes 16B chunks at panel rows srow, srow+128.
  // source col pre-swizzled so linear global_load_lds + swizzled ds_read agree.
  const int srow = tid >> 2;
  const int sg = (tid & 3) ^ ((srow >> 1) & 3);
  const f16* pA1 = A + (size_t)(bm * 256 + srow) * K + sg * 8;
  const f16* pA2 = pA1 + (size_t)128 * K;
  const f16* pB1;
  const f16* pB2;
  if constexpr (EPI == 3) {
    pB1 = BT + (size_t)(bn * 128 + srow) * K + sg * 8;
    pB2 = aux + (size_t)(bn * 128 + srow) * K + sg * 8;
  } else {
    pB1 = BT + (size_t)(bn * 256 + srow) * K + sg * 8;
    pB2 = pB1 + (size_t)128 * K;
  }

  auto stage = [&](int op, int kh, int buf, int kt) {
    const int kb = kt * 64 + kh * 32;
    const f16* s1 = (op ? pB1 : pA1) + kb;
    const f16* s2 = (op ? pB2 : pA2) + kb;
    f16* dst = lds + ((buf << 2) + (kh << 1) + op) * 8192 + tid * 8;
    gload_lds16(s1, dst);
    gload_lds16(s2, dst + 4096);
  };

  // frag read offsets: row*32 elts + swizzled 16B slot (constant per thread)
  const int fcol = (lk ^ ((l15 >> 1) & 3)) << 3;
  const int aoff = (wm * 128 + l15) * 32 + fcol;          // A unit base + mi*512
  const int boff = 8192 + (wn * 64 + l15) * 32 + fcol;    // B unit base + ni*512

  f32x4 acc[8][4] = {};

  // prologue: A0(0), B0(0), A1(0), B1(0), A0(1). vmcnt(6) -> first 2 units landed.
  stage(0, 0, 0, 0);
  stage(1, 0, 0, 0);
  stage(0, 1, 0, 0);
  stage(1, 1, 0, 0);
  if (NT > 1) stage(0, 0, 1, 1);
  asm volatile("s_waitcnt vmcnt(6)" ::: "memory");
  __builtin_amdgcn_s_barrier();
  asm volatile("" ::: "memory");

  for (int t = 0; t < NT; ++t) {
    const int buf = t & 1, nbuf = buf ^ 1;
    const f16* lb0 = lds + buf * 32768;   // kh0 units
    const f16* lb1 = lb0 + 16384;         // kh1 units
    {
      // ---- pair 1: kh0 (A lo+hi, B; 32 MFMA) ----
      f16x8 a1[4], b[4], a2[4];
#pragma unroll
      for (int i = 0; i < 4; ++i) a1[i] = *(const f16x8*)(lb0 + aoff + i * 512);
#pragma unroll
      for (int i = 0; i < 4; ++i) b[i] = *(const f16x8*)(lb0 + boff + i * 512);
#pragma unroll
      for (int i = 0; i < 4; ++i) a2[i] = *(const f16x8*)(lb0 + aoff + (4 + i) * 512);
      if (t + 1 < NT) stage(1, 0, nbuf, t + 1);
      __builtin_amdgcn_s_setprio(1);
#pragma unroll
      for (int mi = 0; mi < 4; ++mi)
#pragma unroll
        for (int ni = 0; ni < 4; ++ni)
          acc[mi][ni] = __builtin_amdgcn_mfma_f32_16x16x32_f16(a1[mi], b[ni], acc[mi][ni], 0, 0, 0);
      __builtin_amdgcn_s_setprio(0);
      if (t + 1 < NT) stage(0, 1, nbuf, t + 1);
      __builtin_amdgcn_s_setprio(1);
#pragma unroll
      for (int mi = 0; mi < 4; ++mi)
#pragma unroll
        for (int ni = 0; ni < 4; ++ni)
          acc[4 + mi][ni] = __builtin_amdgcn_mfma_f32_16x16x32_f16(a2[mi], b[ni], acc[4 + mi][ni], 0, 0, 0);
      __builtin_amdgcn_s_setprio(0);
    }
    // guard: A1(t),B1(t) staged for pair 2 (exact count at tail)
    if (t + 1 < NT) asm volatile("s_waitcnt vmcnt(6)" ::: "memory");
    else            asm volatile("s_waitcnt vmcnt(0)" ::: "memory");
    __builtin_amdgcn_s_barrier();
    asm volatile("" ::: "memory");
    {
      // ---- pair 2: kh1 ----
      f16x8 a1[4], b[4], a2[4];
#pragma unroll
      for (int i = 0; i < 4; ++i) a1[i] = *(const f16x8*)(lb1 + aoff + i * 512);
#pragma unroll
      for (int i = 0; i < 4; ++i) b[i] = *(const f16x8*)(lb1 + boff + i * 512);
#pragma unroll
      for (int i = 0; i < 4; ++i) a2[i] = *(const f16x8*)(lb1 + aoff + (4 + i) * 512);
      if (t + 1 < NT) stage(1, 1, nbuf, t + 1);
      __builtin_amdgcn_s_setprio(1);
#pragma unroll
      for (int mi = 0; mi < 4; ++mi)
#pragma unroll
        for (int ni = 0; ni < 4; ++ni)
          acc[mi][ni] = __builtin_amdgcn_mfma_f32_16x16x32_f16(a1[mi], b[ni], acc[mi][ni], 0, 0, 0);
      __builtin_amdgcn_s_setprio(0);
      if (t + 2 < NT) stage(0, 0, buf, t + 2);  // A-kh0(t) dead since pair-1 reads
      __builtin_amdgcn_s_setprio(1);
#pragma unroll
      for (int mi = 0; mi < 4; ++mi)
#pragma unroll
        for (int ni = 0; ni < 4; ++ni)
          acc[4 + mi][ni] = __builtin_amdgcn_mfma_f32_16x16x32_f16(a2[mi], b[ni], acc[4 + mi][ni], 0, 0, 0);
      __builtin_amdgcn_s_setprio(0);
    }
    // guard: A0(t+1),B0(t+1) staged for next pair-1 (exact count at tail)
    if (t + 2 < NT)      asm volatile("s_waitcnt vmcnt(6)" ::: "memory");
    else if (t + 1 < NT) asm volatile("s_waitcnt vmcnt(4)" ::: "memory");
    else                 asm volatile("s_waitcnt vmcnt(0)" ::: "memory");
    __builtin_amdgcn_s_barrier();
    asm volatile("" ::: "memory");
  }

  // epilogue: C/D map col=l15, row=lk*4+i (m89-verified)
  if constexpr (EPI == 3) {
    // gate waves (wn<2) write gelu(g) to padded f16 LDS; up waves multiply.
    constexpr int XP = 136;  // row pad: stride 272 B -> <=2-way bank aliasing
    __syncthreads();
    f16* xls = lds;  // [256][136] f16 = 69.6 KB
    if (wn < 2) {
#pragma unroll
      for (int mi = 0; mi < 8; ++mi)
#pragma unroll
        for (int ni = 0; ni < 4; ++ni)
#pragma unroll
          for (int i = 0; i < 4; ++i) {
            int row = wm * 128 + mi * 16 + lk * 4 + i;
            int col = wn * 64 + ni * 16 + l15;
            float v = acc[mi][ni][i];
            v = 0.5f * v * (1.0f + erff(v * 0.70710678118654752f));
            xls[row * XP + col] = (f16)v;
          }
    }
    __syncthreads();
    if (wn >= 2) {
#pragma unroll
      for (int mi = 0; mi < 8; ++mi)
#pragma unroll
        for (int ni = 0; ni < 4; ++ni)
#pragma unroll
          for (int i = 0; i < 4; ++i) {
            int row = wm * 128 + mi * 16 + lk * 4 + i;
            int colg = (wn - 2) * 64 + ni * 16 + l15;
            float g = (float)xls[row * XP + colg];
            float v = g * acc[mi][ni][i];
            C[(size_t)(bm * 256 + row) * N + bn * 128 + colg] = (f16)v;
          }
    }
  } else {
#pragma unroll
    for (int mi = 0; mi < 8; ++mi) {
#pragma unroll
      for (int ni = 0; ni < 4; ++ni) {
#pragma unroll
        for (int i = 0; i < 4; ++i) {
          int row = bm * 256 + wm * 128 + mi * 16 + lk * 4 + i;
          int col = bn * 256 + wn * 64 + ni * 16 + l15;
          size_t idx = (size_t)row * N + col;
          float v = acc[mi][ni][i];
          if constexpr (EPI == 1) {
            v = 0.5f * v * (1.0f + erff(v * 0.70710678118654752f));
          } else if constexpr (EPI == 2) {
            v *= (float)aux[idx];
          }
          C[idx] = (f16)v;
        }
      }
    }
  }
}

// ---------------------------------------------------------------------------
// Flash attention, sliding window 1024, GQA rep=2.
// grid (L/64, H, B), block 256 (4 waves, 16 q-rows each). KV tile = 32.
__global__ __launch_bounds__(256) void flash_attn_k(
    const f16* __restrict__ q_g, const f16* __restrict__ k_g,
    const f16* __restrict__ vt, f16* __restrict__ ctx) {
  constexpr int KP = 264, VP = 40, PP = 40;
  __shared__ f16 Ks[32 * KP];
  __shared__ f16 Vs[256 * VP];
  __shared__ f16 Ps[4][16 * PP];
  const int qt = blockIdx.x, h = blockIdx.y, b = blockIdx.z;
  const int tid = threadIdx.x, w = tid >> 6, l = tid & 63;
  const int l15 = l & 15, lk = l >> 4;
  const int kv = h >> 1;

  f16x8 aq[8];
  const int qrow = qt * 64 + w * 16 + l15;
  const f16* qp = q_g + (size_t)(b * 2048 + qrow) * 2048 + h * 256 + lk * 8;
#pragma unroll
  for (int kc = 0; kc < 8; ++kc) aq[kc] = *(const f16x8*)(qp + kc * 32);

  f32x4 o[16] = {};
  float mrow[4] = {-1e30f, -1e30f, -1e30f, -1e30f};
  float lrow[4] = {0.f, 0.f, 0.f, 0.f};

  int kt_lo = 2 * qt - 32; if (kt_lo < 0) kt_lo = 0;
  const int kt_hi = 2 * qt + 1;
  const int iqb = qt * 64 + w * 16 + lk * 4;

  for (int kt = kt_lo; kt <= kt_hi; ++kt) {
    __syncthreads();
#pragma unroll
    for (int it = 0; it < 4; ++it) {
      int ch = tid + it * 256;
      int jl = ch >> 5, kcc = (ch & 31) * 8;
      *(f16x8*)&Ks[jl * KP + kcc] = *(const f16x8*)(
          k_g + (size_t)(b * 2048 + kt * 32 + jl) * 1024 + kv * 256 + kcc);
      int d = ch >> 2, tc = (ch & 3) * 8;
      *(f16x8*)&Vs[d * VP + tc] = *(const f16x8*)(
          vt + ((size_t)(b * 4 + kv) * 256 + d) * 2048 + kt * 32 + tc);
    }
    __syncthreads();
    // S = Q K^T  (16q x 32k per wave)
    f32x4 s[2] = {};
#pragma unroll
    for (int ct = 0; ct < 2; ++ct)
#pragma unroll
      for (int kc = 0; kc < 8; ++kc) {
        f16x8 bk = *(const f16x8*)&Ks[(ct * 16 + l15) * KP + kc * 32 + lk * 8];
        s[ct] = __builtin_amdgcn_mfma_f32_16x16x32_f16(aq[kc], bk, s[ct], 0, 0, 0);
      }
    // mask + online softmax
    float pm[4] = {-1e30f, -1e30f, -1e30f, -1e30f};
#pragma unroll
    for (int ct = 0; ct < 2; ++ct)
#pragma unroll
      for (int i = 0; i < 4; ++i) {
        int iq = iqb + i;
        int j = kt * 32 + ct * 16 + l15;
        bool valid = (j <= iq) && (j > iq - 1024);
        float sv = valid ? s[ct][i] : -1e30f;
        s[ct][i] = sv;
        pm[i] = fmaxf(pm[i], sv);
      }
#pragma unroll
    for (int i = 0; i < 4; ++i)
#pragma unroll
      for (int off = 1; off < 16; off <<= 1)
        pm[i] = fmaxf(pm[i], __shfl_xor(pm[i], off, 64));
    float corr[4], rsum[4];
#pragma unroll
    for (int i = 0; i < 4; ++i) {
      float mn = fmaxf(mrow[i], pm[i]);
      corr[i] = __expf(mrow[i] - mn);
      mrow[i] = mn;
      rsum[i] = 0.f;
    }
#pragma unroll
    for (int ct = 0; ct < 2; ++ct)
#pragma unroll
      for (int i = 0; i < 4; ++i) {
        float p = (s[ct][i] > -1e29f) ? __expf(s[ct][i] - mrow[i]) : 0.f;
        s[ct][i] = p;
        rsum[i] += p;
      }
#pragma unroll
    for (int i = 0; i < 4; ++i) {
#pragma unroll
      for (int off = 1; off < 16; off <<= 1) rsum[i] += __shfl_xor(rsum[i], off, 64);
      lrow[i] = lrow[i] * corr[i] + rsum[i];
    }
#pragma unroll
    for (int dt = 0; dt < 16; ++dt)
#pragma unroll
      for (int i = 0; i < 4; ++i) o[dt][i] *= corr[i];
    // P -> LDS (f16)
#pragma unroll
    for (int ct = 0; ct < 2; ++ct)
#pragma unroll
      for (int i = 0; i < 4; ++i)
        Ps[w][(lk * 4 + i) * PP + ct * 16 + l15] = (f16)s[ct][i];
    __syncthreads();
    // O += P V
    f16x8 pa = *(const f16x8*)&Ps[w][l15 * PP + lk * 8];
#pragma unroll
    for (int dt = 0; dt < 16; ++dt) {
      f16x8 bv = *(const f16x8*)&Vs[(dt * 16 + l15) * VP + lk * 8];
      o[dt] = __builtin_amdgcn_mfma_f32_16x16x32_f16(pa, bv, o[dt], 0, 0, 0);
    }
  }
  float inv[4];
#pragma unroll
  for (int i = 0; i < 4; ++i) inv[i] = 1.0f / lrow[i];
  f16* op = ctx + (size_t)(b * 2048 + qt * 64 + w * 16 + lk * 4) * 2048 + h * 256 + l15;
#pragma unroll
  for (int dt = 0; dt < 16; ++dt)
#pragma unroll
    for (int i = 0; i < 4; ++i)
      op[(size_t)i * 2048 + dt * 16] = (f16)(o[dt][i] * inv[i]);
}

// ---------------------------------------------------------------------------
extern "C" void kernel_launch(void* const* d_in, const int* in_sizes, int n_in,
                              void* d_out, int out_size, void* d_ws, size_t ws_size,
                              hipStream_t stream) {
  const float* x = (const float*)d_in[0];
  const int* positions = (const int*)d_in[1];
  const float* wq = (const float*)d_in[2];
  const float* wk = (const float*)d_in[3];
  const float* wv = (const float*)d_in[4];
  const float* wo = (const float*)d_in[5];
  const float* q_scale = (const float*)d_in[6];
  const float* k_scale = (const float*)d_in[7];
  const float* pre_attn = (const float*)d_in[8];
  const float* post_attn = (const float*)d_in[9];
  const float* pre_ffw = (const float*)d_in[10];
  const float* post_ffw = (const float*)d_in[11];
  const float* w_gate = (const float*)d_in[12];
  const float* w_up = (const float*)d_in[13];
  const float* w_down = (const float*)d_in[14];
  float* out = (float*)d_out;

  // one-time: allow 128KB dynamic LDS on the GEMM (attribute set, not a stream op)
  static bool s_attr = []() {
    hipFuncSetAttribute(reinterpret_cast<const void*>(&gemm256<0>),
                        hipFuncAttributeMaxDynamicSharedMemorySize, 131072);
    hipFuncSetAttribute(reinterpret_cast<const void*>(&gemm256<1>),
                        hipFuncAttributeMaxDynamicSharedMemorySize, 131072);
    hipFuncSetAttribute(reinterpret_cast<const void*>(&gemm256<2>),
                        hipFuncAttributeMaxDynamicSharedMemorySize, 131072);
    hipFuncSetAttribute(reinterpret_cast<const void*>(&gemm256<3>),
                        hipFuncAttributeMaxDynamicSharedMemorySize, 131072);
    return true;
  }();
  (void)s_attr;

  // ---- workspace layout ----
  const size_t WT_BIG   = (size_t)20480 * 2560 * 2;  // gate^T + up^T resident
  const size_t WT_SMALL = (size_t)10240 * 2560 * 2;
  const size_t TAB_B = (size_t)2048 * 256 * 4;
  const size_t H_B   = (size_t)4096 * 2560 * 2;
  const size_t ACT_B = (size_t)92280832;
  auto aln = [](size_t v) { return (v + 255) & ~(size_t)255; };
  const bool big = ws_size >= aln(WT_BIG) + aln(TAB_B) + aln(H_B) + aln(ACT_B);

  char* ws = (char*)d_ws;
  size_t off = 0;
  auto alloc = [&](size_t bytes) {
    char* p = ws + off;
    off += (bytes + 255) & ~(size_t)255;
    return p;
  };
  f16* wT    = (f16*)alloc(big ? WT_BIG : WT_SMALL);
  float* tab = (float*)alloc(TAB_B);
  f16* h     = (f16*)alloc(H_B);
  char* act  = alloc(ACT_B);
  // attention-phase overlays inside act:
  f16* qkv    = (f16*)(act);                                    // 33.5 MB
  f16* q_g    = (f16*)(act + (size_t)33554432);                 // 16.8 MB
  f16* k_g    = (f16*)(act + (size_t)33554432 + 16777216);      //  8.4 MB
  f16* v_n    = (f16*)(act + (size_t)33554432 + 16777216 + 8388608);
  f16* vtb    = (f16*)(act + (size_t)33554432 + 16777216 + 2 * 8388608);
  f16* ctx    = (f16*)(act + (size_t)33554432 + 16777216 + 3 * 8388608);
  f16* attn_o = (f16*)(act);            // reuse qkv slot (dead after norm_rope)
  // ffw-phase overlays:
  f16* gbuf = (f16*)(act);              // 83.9 MB spans whole act region
  f16* ffw  = h;                        // h dead after it's consumed as GEMM A
  f16* wuT  = wT + (size_t)10240 * 2560;  // big path only
  (void)in_sizes; (void)n_in; (void)out_size;

  dim3 tb(32, 8);
  rope_table_k<<<1024, 256, 0, stream>>>(tab);

  // ---- attention path ----
  rmsnorm_f32_f16<<<4096, 256, 0, stream>>>(x, pre_attn, h);
  // wq|wk|wv -> wT as [4096][2560] (q rows 0-2047, k 2048-3071, v 3072-4095)
  transpose_w<<<dim3(2048 / 32, 2560 / 32), tb, 0, stream>>>(wq, wT, 2560, 2048);
  transpose_w<<<dim3(1024 / 32, 2560 / 32), tb, 0, stream>>>(wk, wT + (size_t)2048 * 2560, 2560, 1024);
  transpose_w<<<dim3(1024 / 32, 2560 / 32), tb, 0, stream>>>(wv, wT + (size_t)3072 * 2560, 2560, 1024);
  gemm256<0><<<dim3(4096 / 256, 4096 / 256), 512, 131072, stream>>>(h, wT, qkv, nullptr, 4096, 4096, 2560);
  norm_rope_k<<<4096, 256, 0, stream>>>(qkv, positions, q_scale, k_scale, tab, q_g, k_g, v_n);
  transpose_v_k<<<dim3(2048 / 32, 256 / 32, 8), tb, 0, stream>>>(v_n, vtb);
  flash_attn_k<<<dim3(32, 8, 2), 256, 0, stream>>>(q_g, k_g, vtb, ctx);
  transpose_w<<<dim3(2560 / 32, 2048 / 32), tb, 0, stream>>>(wo, wT, 2048, 2560);
  gemm256<0><<<dim3(2560 / 256, 4096 / 256), 512, 131072, stream>>>(ctx, wT, attn_o, nullptr, 4096, 2560, 2048);
  residual_rmsnorm<<<4096, 256, 0, stream>>>(x, attn_o, post_attn, out);

  // ---- ffw path ----
  rmsnorm_f32_f16<<<4096, 256, 0, stream>>>(out, pre_ffw, h);
  if (big) {
    // fused gate+up: grid 80x16 = 1280 blocks = 5.0 x 256 CUs (no tail)
    transpose_w<<<dim3(10240 / 32, 2560 / 32), tb, 0, stream>>>(w_gate, wT, 2560, 10240);
    transpose_w<<<dim3(10240 / 32, 2560 / 32), tb, 0, stream>>>(w_up, wuT, 2560, 10240);
    gemm256<3><<<dim3(80, 16), 512, 131072, stream>>>(h, wT, gbuf, wuT, 4096, 10240, 2560);
  } else {
    transpose_w<<<dim3(10240 / 32, 2560 / 32), tb, 0, stream>>>(w_gate, wT, 2560, 10240);
    gemm256<1><<<dim3(10240 / 256, 4096 / 256), 512, 131072, stream>>>(h, wT, gbuf, nullptr, 4096, 10240, 2560);
    transpose_w<<<dim3(10240 / 32, 2560 / 32), tb, 0, stream>>>(w_up, wT, 2560, 10240);
    gemm256<2><<<dim3(10240 / 256, 4096 / 256), 512, 131072, stream>>>(h, wT, gbuf, gbuf, 4096, 10240, 2560);
  }
  transpose_w<<<dim3(2560 / 32, 10240 / 32), tb, 0, stream>>>(w_down, wT, 10240, 2560);
  gemm256<0><<<dim3(2560 / 256, 4096 / 256), 512, 131072, stream>>>(gbuf, wT, ffw, nullptr, 4096, 2560, 10240);
  residual_rmsnorm<<<4096, 256, 0, stream>>>(out, ffw, post_ffw, out);
}

// Round 5
// 1195.955 us; speedup vs baseline: 1.0525x; 1.0015x over previous
//
#include <hip/hip_runtime.h>
#include <math.h>

#define DEV __device__ __forceinline__

typedef _Float16 f16;
typedef _Float16 f16x8 __attribute__((ext_vector_type(8)));
typedef _Float16 f16x4 __attribute__((ext_vector_type(4)));
typedef float f32x4 __attribute__((ext_vector_type(4)));

DEV void gload_lds16(const void* g, void* l) {
  __builtin_amdgcn_global_load_lds(
      (const __attribute__((address_space(1))) void*)g,
      (__attribute__((address_space(3))) void*)l, 16, 0, 0);
}

// ---------------------------------------------------------------------------
// Weight transpose + f32->f16 convert: src [R][C] f32 -> dst [C][R] f16
// grid (C/32, R/32), block (32,8)
__global__ void transpose_w(const float* __restrict__ src, f16* __restrict__ dst,
                            int R, int C) {
  __shared__ float tile[32][33];
  int c0 = blockIdx.x * 32, r0 = blockIdx.y * 32;
  int tx = threadIdx.x, ty = threadIdx.y;
#pragma unroll
  for (int j = 0; j < 32; j += 8)
    tile[ty + j][tx] = src[(size_t)(r0 + ty + j) * C + c0 + tx];
  __syncthreads();
#pragma unroll
  for (int j = 0; j < 32; j += 8)
    dst[(size_t)(c0 + ty + j) * R + r0 + tx] = (f16)tile[tx][ty + j];
}

// ---------------------------------------------------------------------------
// RoPE sin/cos table: tab[pos][0..127]=sin, [128..255]=cos. 2048 pos x 128 j
__global__ void rope_table_k(float* __restrict__ tab) {
  int idx = blockIdx.x * 256 + threadIdx.x;  // 1024 blocks -> 262144 = 2048*128
  int pos = idx >> 7, j = idx & 127;
  float ts = powf(10000.0f, (float)j * (1.0f / 128.0f));
  float ang = (float)pos / ts;
  tab[pos * 256 + j] = sinf(ang);
  tab[pos * 256 + 128 + j] = cosf(ang);
}

// ---------------------------------------------------------------------------
// h = rmsnorm(in, scale) -> f16. one block per row, D=2560
__global__ __launch_bounds__(256) void rmsnorm_f32_f16(
    const float* __restrict__ in, const float* __restrict__ scale,
    f16* __restrict__ out) {
  constexpr int D = 2560, N4 = D / 4;
  const int m = blockIdx.x, tid = threadIdx.x;
  const float* row = in + (size_t)m * D;
  float vals[12];
  float ss = 0.f;
#pragma unroll
  for (int it = 0; it < 3; ++it) {
    int c4 = tid + it * 256;
    if (c4 < N4) {
      float4 v = *(const float4*)(row + c4 * 4);
      vals[it * 4 + 0] = v.x; vals[it * 4 + 1] = v.y;
      vals[it * 4 + 2] = v.z; vals[it * 4 + 3] = v.w;
      ss += v.x * v.x + v.y * v.y + v.z * v.z + v.w * v.w;
    }
  }
#pragma unroll
  for (int off = 32; off; off >>= 1) ss += __shfl_xor(ss, off, 64);
  __shared__ float red[4];
  if ((tid & 63) == 0) red[tid >> 6] = ss;
  __syncthreads();
  float rs = rsqrtf((red[0] + red[1] + red[2] + red[3]) * (1.0f / D) + 1e-6f);
#pragma unroll
  for (int it = 0; it < 3; ++it) {
    int c4 = tid + it * 256;
    if (c4 < N4) {
      float4 sc = *(const float4*)(scale + c4 * 4);
      f16x4 o;
      o[0] = (f16)(vals[it * 4 + 0] * rs * sc.x);
      o[1] = (f16)(vals[it * 4 + 1] * rs * sc.y);
      o[2] = (f16)(vals[it * 4 + 2] * rs * sc.z);
      o[3] = (f16)(vals[it * 4 + 3] * rs * sc.w);
      *(f16x4*)(out + (size_t)m * D + c4 * 4) = o;
    }
  }
}

// out = x + rmsnorm(y, scale); safe when out aliases x (per-thread RMW)
__global__ __launch_bounds__(256) void residual_rmsnorm(
    const float* x, const f16* __restrict__ y,
    const float* __restrict__ scale, float* out) {
  constexpr int D = 2560, N4 = D / 4;
  const int m = blockIdx.x, tid = threadIdx.x;
  const f16* yr = y + (size_t)m * D;
  float yv[12];
  float ss = 0.f;
#pragma unroll
  for (int it = 0; it < 3; ++it) {
    int c4 = tid + it * 256;
    if (c4 < N4) {
      f16x4 u = *(const f16x4*)(yr + c4 * 4);
      float a = (float)u[0], b = (float)u[1], c = (float)u[2], d = (float)u[3];
      yv[it * 4 + 0] = a; yv[it * 4 + 1] = b; yv[it * 4 + 2] = c; yv[it * 4 + 3] = d;
      ss += a * a + b * b + c * c + d * d;
    }
  }
#pragma unroll
  for (int off = 32; off; off >>= 1) ss += __shfl_xor(ss, off, 64);
  __shared__ float red[4];
  if ((tid & 63) == 0) red[tid >> 6] = ss;
  __syncthreads();
  float rs = rsqrtf((red[0] + red[1] + red[2] + red[3]) * (1.0f / D) + 1e-6f);
#pragma unroll
  for (int it = 0; it < 3; ++it) {
    int c4 = tid + it * 256;
    if (c4 < N4) {
      float4 xv = *(const float4*)(x + (size_t)m * D + c4 * 4);
      float4 sc = *(const float4*)(scale + c4 * 4);
      float4 o;
      o.x = xv.x + yv[it * 4 + 0] * rs * sc.x;
      o.y = xv.y + yv[it * 4 + 1] * rs * sc.y;
      o.z = xv.z + yv[it * 4 + 2] * rs * sc.z;
      o.w = xv.w + yv[it * 4 + 3] * rs * sc.w;
      *(float4*)(out + (size_t)m * D + c4 * 4) = o;
    }
  }
}

// ---------------------------------------------------------------------------
// Per-head rmsnorm (+RoPE for q,k) on qkv [4096][4096] f16.
// vectors: 0-7 q heads, 8-11 k heads, 12-15 v heads. one block per token.
__global__ __launch_bounds__(256) void norm_rope_k(
    const f16* __restrict__ qkv, const int* __restrict__ positions,
    const float* __restrict__ q_scale, const float* __restrict__ k_scale,
    const float* __restrict__ tab,
    f16* __restrict__ q_g, f16* __restrict__ k_g, f16* __restrict__ v_n) {
  const int m = blockIdx.x;
  const int tid = threadIdx.x, w = tid >> 6, l = tid & 63;
  const int pos = positions[m];
  const float* srow = tab + (size_t)pos * 256;
  const int c0 = l * 4;
  for (int vi = w; vi < 16; vi += 4) {
    f16x4 u = *(const f16x4*)(qkv + (size_t)m * 4096 + vi * 256 + c0);
    float x0 = (float)u[0], x1 = (float)u[1], x2 = (float)u[2], x3 = (float)u[3];
    float ss = x0 * x0 + x1 * x1 + x2 * x2 + x3 * x3;
#pragma unroll
    for (int off = 32; off; off >>= 1) ss += __shfl_xor(ss, off, 64);
    float rs = rsqrtf(ss * (1.0f / 256.0f) + 1e-6f);
    if (vi < 12) {
      const float* sc = (vi < 8) ? q_scale : k_scale;
      float4 s4 = *(const float4*)(sc + c0);
      float n0 = x0 * rs * s4.x, n1 = x1 * rs * s4.y;
      float n2 = x2 * rs * s4.z, n3 = x3 * rs * s4.w;
      float p0 = __shfl_xor(n0, 32, 64), p1 = __shfl_xor(n1, 32, 64);
      float p2 = __shfl_xor(n2, 32, 64), p3 = __shfl_xor(n3, 32, 64);
      int j0 = c0 & 127;
      float4 sn = *(const float4*)(srow + j0);
      float4 cs = *(const float4*)(srow + 128 + j0);
      float sgn = (l < 32) ? -1.0f : 1.0f;
      f16x4 o;
      o[0] = (f16)(n0 * cs.x + sgn * p0 * sn.x);
      o[1] = (f16)(n1 * cs.y + sgn * p1 * sn.y);
      o[2] = (f16)(n2 * cs.z + sgn * p2 * sn.z);
      o[3] = (f16)(n3 * cs.w + sgn * p3 * sn.w);
      if (vi < 8) *(f16x4*)(q_g + (size_t)m * 2048 + vi * 256 + c0) = o;
      else        *(f16x4*)(k_g + (size_t)m * 1024 + (vi - 8) * 256 + c0) = o;
    } else {
      f16x4 o;
      o[0] = (f16)(x0 * rs); o[1] = (f16)(x1 * rs);
      o[2] = (f16)(x2 * rs); o[3] = (f16)(x3 * rs);
      *(f16x4*)(v_n + (size_t)m * 1024 + (vi - 12) * 256 + c0) = o;
    }
  }
}

// v_n [4096][1024] -> vt [B*KV=8][256][2048] (per-(b,kv) transposed)
__global__ void transpose_v_k(const f16* __restrict__ v_n, f16* __restrict__ vt) {
  __shared__ f16 tile[32][33];
  int bkv = blockIdx.z;
  int b = bkv >> 2, kv = bkv & 3;
  int t0 = blockIdx.x * 32, d0 = blockIdx.y * 32;
  int tx = threadIdx.x, ty = threadIdx.y;
#pragma unroll
  for (int j = 0; j < 32; j += 8)
    tile[ty + j][tx] =
        v_n[(size_t)(b * 2048 + t0 + ty + j) * 1024 + kv * 256 + d0 + tx];
  __syncthreads();
#pragma unroll
  for (int j = 0; j < 32; j += 8)
    vt[((size_t)bkv * 256 + d0 + ty + j) * 2048 + t0 + tx] = tile[tx][ty + j];
}

// ---------------------------------------------------------------------------
// 256x256 GEMM, round-2/4 schedule (best measured): 2 barriers per K-tile,
// counted vmcnt(6)/(4)/(0), per-pair [12 ds_reads; stage; MFMA x16; stage;
// MFMA x16]. A [M][K] f16, BT [N][K] f16, C [M][N] f16. 512 threads = 8
// waves (2Mx4N), BK=64 staged as 4x 16KB units, double-buffered (128KB LDS),
// XOR-swizzled via pre-swizzled global source.
// GRID DECODE (round-locality): bm = orig & 15, bn = orig >> 4. M==4096 at
// every call site (16 bm tiles). Each dispatch round of 256 blocks covers
// 16 bn panels x ALL 16 bm -> every staged weight byte is consumed by all
// its bm-consumers within the round it is fetched (round working set
// ~40 MB, L3-resident) instead of being re-streamed from HBM each round.
// XCD locality preserved: XCD x holds bm in {x, x+8} (2 A-panels per L2).
// EPI: 0=store, 1=gelu(exact), 2=mul by aux[idx] (in-place allowed),
// 3=fused gate+up: B-panel rows 0-127 from BT (gate^T), rows 128-255 from
// aux (up^T); epilogue exchanges gelu(gate) via padded f16 LDS and stores
// gelu(g)*u to C cols [bn*128, bn*128+128).
// Requires K%64==0, M==4096.
template <int EPI>
__global__ __launch_bounds__(512, 2) void gemm256(
    const f16* __restrict__ A, const f16* __restrict__ BT,
    f16* __restrict__ C, const f16* __restrict__ aux, int M, int N, int K) {
  extern __shared__ __align__(16) f16 lds[];  // 131072 B
  const int tid = threadIdx.x;
  const int w = tid >> 6, l = tid & 63;
  const int l15 = l & 15, lk = l >> 4;
  const int wm = w >> 2, wn = w & 3;  // 2 x 4 wave grid

  // round-locality decode (see header comment)
  const int orig = blockIdx.y * gridDim.x + blockIdx.x;
  const int bm = orig & 15;
  const int bn = orig >> 4;

  const int NT = K >> 6;

  // staging: thread writes 16B chunks at panel rows srow, srow+128.
  // source col pre-swizzled so linear global_load_lds + swizzled ds_read agree.
  const int srow = tid >> 2;
  const int sg = (tid & 3) ^ ((srow >> 1) & 3);
  const f16* pA1 = A + (size_t)(bm * 256 + srow) * K + sg * 8;
  const f16* pA2 = pA1 + (size_t)128 * K;
  const f16* pB1;
  const f16* pB2;
  if constexpr (EPI == 3) {
    pB1 = BT + (size_t)(bn * 128 + srow) * K + sg * 8;
    pB2 = aux + (size_t)(bn * 128 + srow) * K + sg * 8;
  } else {
    pB1 = BT + (size_t)(bn * 256 + srow) * K + sg * 8;
    pB2 = pB1 + (size_t)128 * K;
  }

  auto stage = [&](int op, int kh, int buf, int kt) {
    const int kb = kt * 64 + kh * 32;
    const f16* s1 = (op ? pB1 : pA1) + kb;
    const f16* s2 = (op ? pB2 : pA2) + kb;
    f16* dst = lds + ((buf << 2) + (kh << 1) + op) * 8192 + tid * 8;
    gload_lds16(s1, dst);
    gload_lds16(s2, dst + 4096);
  };

  // frag read offsets: row*32 elts + swizzled 16B slot (constant per thread)
  const int fcol = (lk ^ ((l15 >> 1) & 3)) << 3;
  const int aoff = (wm * 128 + l15) * 32 + fcol;          // A unit base + mi*512
  const int boff = 8192 + (wn * 64 + l15) * 32 + fcol;    // B unit base + ni*512

  f32x4 acc[8][4] = {};

  // prologue: A0(0), B0(0), A1(0), B1(0), A0(1). vmcnt(6) -> first 2 units landed.
  stage(0, 0, 0, 0);
  stage(1, 0, 0, 0);
  stage(0, 1, 0, 0);
  stage(1, 1, 0, 0);
  if (NT > 1) stage(0, 0, 1, 1);
  asm volatile("s_waitcnt vmcnt(6)" ::: "memory");
  __builtin_amdgcn_s_barrier();
  asm volatile("" ::: "memory");

  for (int t = 0; t < NT; ++t) {
    const int buf = t & 1, nbuf = buf ^ 1;
    const f16* lb0 = lds + buf * 32768;   // kh0 units
    const f16* lb1 = lb0 + 16384;         // kh1 units
    {
      // ---- pair 1: kh0 (A lo+hi, B; 32 MFMA) ----
      f16x8 a1[4], b[4], a2[4];
#pragma unroll
      for (int i = 0; i < 4; ++i) a1[i] = *(const f16x8*)(lb0 + aoff + i * 512);
#pragma unroll
      for (int i = 0; i < 4; ++i) b[i] = *(const f16x8*)(lb0 + boff + i * 512);
#pragma unroll
      for (int i = 0; i < 4; ++i) a2[i] = *(const f16x8*)(lb0 + aoff + (4 + i) * 512);
      if (t + 1 < NT) stage(1, 0, nbuf, t + 1);
      __builtin_amdgcn_s_setprio(1);
#pragma unroll
      for (int mi = 0; mi < 4; ++mi)
#pragma unroll
        for (int ni = 0; ni < 4; ++ni)
          acc[mi][ni] = __builtin_amdgcn_mfma_f32_16x16x32_f16(a1[mi], b[ni], acc[mi][ni], 0, 0, 0);
      __builtin_amdgcn_s_setprio(0);
      if (t + 1 < NT) stage(0, 1, nbuf, t + 1);
      __builtin_amdgcn_s_setprio(1);
#pragma unroll
      for (int mi = 0; mi < 4; ++mi)
#pragma unroll
        for (int ni = 0; ni < 4; ++ni)
          acc[4 + mi][ni] = __builtin_amdgcn_mfma_f32_16x16x32_f16(a2[mi], b[ni], acc[4 + mi][ni], 0, 0, 0);
      __builtin_amdgcn_s_setprio(0);
    }
    // guard: A1(t),B1(t) staged for pair 2 (exact count at tail)
    if (t + 1 < NT) asm volatile("s_waitcnt vmcnt(6)" ::: "memory");
    else            asm volatile("s_waitcnt vmcnt(0)" ::: "memory");
    __builtin_amdgcn_s_barrier();
    asm volatile("" ::: "memory");
    {
      // ---- pair 2: kh1 ----
      f16x8 a1[4], b[4], a2[4];
#pragma unroll
      for (int i = 0; i < 4; ++i) a1[i] = *(const f16x8*)(lb1 + aoff + i * 512);
#pragma unroll
      for (int i = 0; i < 4; ++i) b[i] = *(const f16x8*)(lb1 + boff + i * 512);
#pragma unroll
      for (int i = 0; i < 4; ++i) a2[i] = *(const f16x8*)(lb1 + aoff + (4 + i) * 512);
      if (t + 1 < NT) stage(1, 1, nbuf, t + 1);
      __builtin_amdgcn_s_setprio(1);
#pragma unroll
      for (int mi = 0; mi < 4; ++mi)
#pragma unroll
        for (int ni = 0; ni < 4; ++ni)
          acc[mi][ni] = __builtin_amdgcn_mfma_f32_16x16x32_f16(a1[mi], b[ni], acc[mi][ni], 0, 0, 0);
      __builtin_amdgcn_s_setprio(0);
      if (t + 2 < NT) stage(0, 0, buf, t + 2);  // A-kh0(t) dead since pair-1 reads
      __builtin_amdgcn_s_setprio(1);
#pragma unroll
      for (int mi = 0; mi < 4; ++mi)
#pragma unroll
        for (int ni = 0; ni < 4; ++ni)
          acc[4 + mi][ni] = __builtin_amdgcn_mfma_f32_16x16x32_f16(a2[mi], b[ni], acc[4 + mi][ni], 0, 0, 0);
      __builtin_amdgcn_s_setprio(0);
    }
    // guard: A0(t+1),B0(t+1) staged for next pair-1 (exact count at tail)
    if (t + 2 < NT)      asm volatile("s_waitcnt vmcnt(6)" ::: "memory");
    else if (t + 1 < NT) asm volatile("s_waitcnt vmcnt(4)" ::: "memory");
    else                 asm volatile("s_waitcnt vmcnt(0)" ::: "memory");
    __builtin_amdgcn_s_barrier();
    asm volatile("" ::: "memory");
  }

  // epilogue: C/D map col=l15, row=lk*4+i (m89-verified)
  if constexpr (EPI == 3) {
    // gate waves (wn<2) write gelu(g) to padded f16 LDS; up waves multiply.
    constexpr int XP = 136;  // row pad: stride 272 B -> <=2-way bank aliasing
    __syncthreads();
    f16* xls = lds;  // [256][136] f16 = 69.6 KB
    if (wn < 2) {
#pragma unroll
      for (int mi = 0; mi < 8; ++mi)
#pragma unroll
        for (int ni = 0; ni < 4; ++ni)
#pragma unroll
          for (int i = 0; i < 4; ++i) {
            int row = wm * 128 + mi * 16 + lk * 4 + i;
            int col = wn * 64 + ni * 16 + l15;
            float v = acc[mi][ni][i];
            v = 0.5f * v * (1.0f + erff(v * 0.70710678118654752f));
            xls[row * XP + col] = (f16)v;
          }
    }
    __syncthreads();
    if (wn >= 2) {
#pragma unroll
      for (int mi = 0; mi < 8; ++mi)
#pragma unroll
        for (int ni = 0; ni < 4; ++ni)
#pragma unroll
          for (int i = 0; i < 4; ++i) {
            int row = wm * 128 + mi * 16 + lk * 4 + i;
            int colg = (wn - 2) * 64 + ni * 16 + l15;
            float g = (float)xls[row * XP + colg];
            float v = g * acc[mi][ni][i];
            C[(size_t)(bm * 256 + row) * N + bn * 128 + colg] = (f16)v;
          }
    }
  } else {
#pragma unroll
    for (int mi = 0; mi < 8; ++mi) {
#pragma unroll
      for (int ni = 0; ni < 4; ++ni) {
#pragma unroll
        for (int i = 0; i < 4; ++i) {
          int row = bm * 256 + wm * 128 + mi * 16 + lk * 4 + i;
          int col = bn * 256 + wn * 64 + ni * 16 + l15;
          size_t idx = (size_t)row * N + col;
          float v = acc[mi][ni][i];
          if constexpr (EPI == 1) {
            v = 0.5f * v * (1.0f + erff(v * 0.70710678118654752f));
          } else if constexpr (EPI == 2) {
            v *= (float)aux[idx];
          }
          C[idx] = (f16)v;
        }
      }
    }
  }
}

// ---------------------------------------------------------------------------
// Flash attention, sliding window 1024, GQA rep=2.
// grid (L/64, H, B), block 256 (4 waves, 16 q-rows each). KV tile = 32.
__global__ __launch_bounds__(256) void flash_attn_k(
    const f16* __restrict__ q_g, const f16* __restrict__ k_g,
    const f16* __restrict__ vt, f16* __restrict__ ctx) {
  constexpr int KP = 264, VP = 40, PP = 40;
  __shared__ f16 Ks[32 * KP];
  __shared__ f16 Vs[256 * VP];
  __shared__ f16 Ps[4][16 * PP];
  const int qt = blockIdx.x, h = blockIdx.y, b = blockIdx.z;
  const int tid = threadIdx.x, w = tid >> 6, l = tid & 63;
  const int l15 = l & 15, lk = l >> 4;
  const int kv = h >> 1;

  f16x8 aq[8];
  const int qrow = qt * 64 + w * 16 + l15;
  const f16* qp = q_g + (size_t)(b * 2048 + qrow) * 2048 + h * 256 + lk * 8;
#pragma unroll
  for (int kc = 0; kc < 8; ++kc) aq[kc] = *(const f16x8*)(qp + kc * 32);

  f32x4 o[16] = {};
  float mrow[4] = {-1e30f, -1e30f, -1e30f, -1e30f};
  float lrow[4] = {0.f, 0.f, 0.f, 0.f};

  int kt_lo = 2 * qt - 32; if (kt_lo < 0) kt_lo = 0;
  const int kt_hi = 2 * qt + 1;
  const int iqb = qt * 64 + w * 16 + lk * 4;

  for (int kt = kt_lo; kt <= kt_hi; ++kt) {
    __syncthreads();
#pragma unroll
    for (int it = 0; it < 4; ++it) {
      int ch = tid + it * 256;
      int jl = ch >> 5, kcc = (ch & 31) * 8;
      *(f16x8*)&Ks[jl * KP + kcc] = *(const f16x8*)(
          k_g + (size_t)(b * 2048 + kt * 32 + jl) * 1024 + kv * 256 + kcc);
      int d = ch >> 2, tc = (ch & 3) * 8;
      *(f16x8*)&Vs[d * VP + tc] = *(const f16x8*)(
          vt + ((size_t)(b * 4 + kv) * 256 + d) * 2048 + kt * 32 + tc);
    }
    __syncthreads();
    // S = Q K^T  (16q x 32k per wave)
    f32x4 s[2] = {};
#pragma unroll
    for (int ct = 0; ct < 2; ++ct)
#pragma unroll
      for (int kc = 0; kc < 8; ++kc) {
        f16x8 bk = *(const f16x8*)&Ks[(ct * 16 + l15) * KP + kc * 32 + lk * 8];
        s[ct] = __builtin_amdgcn_mfma_f32_16x16x32_f16(aq[kc], bk, s[ct], 0, 0, 0);
      }
    // mask + online softmax
    float pm[4] = {-1e30f, -1e30f, -1e30f, -1e30f};
#pragma unroll
    for (int ct = 0; ct < 2; ++ct)
#pragma unroll
      for (int i = 0; i < 4; ++i) {
        int iq = iqb + i;
        int j = kt * 32 + ct * 16 + l15;
        bool valid = (j <= iq) && (j > iq - 1024);
        float sv = valid ? s[ct][i] : -1e30f;
        s[ct][i] = sv;
        pm[i] = fmaxf(pm[i], sv);
      }
#pragma unroll
    for (int i = 0; i < 4; ++i)
#pragma unroll
      for (int off = 1; off < 16; off <<= 1)
        pm[i] = fmaxf(pm[i], __shfl_xor(pm[i], off, 64));
    float corr[4], rsum[4];
#pragma unroll
    for (int i = 0; i < 4; ++i) {
      float mn = fmaxf(mrow[i], pm[i]);
      corr[i] = __expf(mrow[i] - mn);
      mrow[i] = mn;
      rsum[i] = 0.f;
    }
#pragma unroll
    for (int ct = 0; ct < 2; ++ct)
#pragma unroll
      for (int i = 0; i < 4; ++i) {
        float p = (s[ct][i] > -1e29f) ? __expf(s[ct][i] - mrow[i]) : 0.f;
        s[ct][i] = p;
        rsum[i] += p;
      }
#pragma unroll
    for (int i = 0; i < 4; ++i) {
#pragma unroll
      for (int off = 1; off < 16; off <<= 1) rsum[i] += __shfl_xor(rsum[i], off, 64);
      lrow[i] = lrow[i] * corr[i] + rsum[i];
    }
#pragma unroll
    for (int dt = 0; dt < 16; ++dt)
#pragma unroll
      for (int i = 0; i < 4; ++i) o[dt][i] *= corr[i];
    // P -> LDS (f16)
#pragma unroll
    for (int ct = 0; ct < 2; ++ct)
#pragma unroll
      for (int i = 0; i < 4; ++i)
        Ps[w][(lk * 4 + i) * PP + ct * 16 + l15] = (f16)s[ct][i];
    __syncthreads();
    // O += P V
    f16x8 pa = *(const f16x8*)&Ps[w][l15 * PP + lk * 8];
#pragma unroll
    for (int dt = 0; dt < 16; ++dt) {
      f16x8 bv = *(const f16x8*)&Vs[(dt * 16 + l15) * VP + lk * 8];
      o[dt] = __builtin_amdgcn_mfma_f32_16x16x32_f16(pa, bv, o[dt], 0, 0, 0);
    }
  }
  float inv[4];
#pragma unroll
  for (int i = 0; i < 4; ++i) inv[i] = 1.0f / lrow[i];
  f16* op = ctx + (size_t)(b * 2048 + qt * 64 + w * 16 + lk * 4) * 2048 + h * 256 + l15;
#pragma unroll
  for (int dt = 0; dt < 16; ++dt)
#pragma unroll
    for (int i = 0; i < 4; ++i)
      op[(size_t)i * 2048 + dt * 16] = (f16)(o[dt][i] * inv[i]);
}

// ---------------------------------------------------------------------------
extern "C" void kernel_launch(void* const* d_in, const int* in_sizes, int n_in,
                              void* d_out, int out_size, void* d_ws, size_t ws_size,
                              hipStream_t stream) {
  const float* x = (const float*)d_in[0];
  const int* positions = (const int*)d_in[1];
  const float* wq = (const float*)d_in[2];
  const float* wk = (const float*)d_in[3];
  const float* wv = (const float*)d_in[4];
  const float* wo = (const float*)d_in[5];
  const float* q_scale = (const float*)d_in[6];
  const float* k_scale = (const float*)d_in[7];
  const float* pre_attn = (const float*)d_in[8];
  const float* post_attn = (const float*)d_in[9];
  const float* pre_ffw = (const float*)d_in[10];
  const float* post_ffw = (const float*)d_in[11];
  const float* w_gate = (const float*)d_in[12];
  const float* w_up = (const float*)d_in[13];
  const float* w_down = (const float*)d_in[14];
  float* out = (float*)d_out;

  // one-time: allow 128KB dynamic LDS on the GEMM (attribute set, not a stream op)
  static bool s_attr = []() {
    hipFuncSetAttribute(reinterpret_cast<const void*>(&gemm256<0>),
                        hipFuncAttributeMaxDynamicSharedMemorySize, 131072);
    hipFuncSetAttribute(reinterpret_cast<const void*>(&gemm256<1>),
                        hipFuncAttributeMaxDynamicSharedMemorySize, 131072);
    hipFuncSetAttribute(reinterpret_cast<const void*>(&gemm256<2>),
                        hipFuncAttributeMaxDynamicSharedMemorySize, 131072);
    hipFuncSetAttribute(reinterpret_cast<const void*>(&gemm256<3>),
                        hipFuncAttributeMaxDynamicSharedMemorySize, 131072);
    return true;
  }();
  (void)s_attr;

  // ---- workspace layout ----
  const size_t WT_BIG   = (size_t)20480 * 2560 * 2;  // gate^T + up^T resident
  const size_t WT_SMALL = (size_t)10240 * 2560 * 2;
  const size_t TAB_B = (size_t)2048 * 256 * 4;
  const size_t H_B   = (size_t)4096 * 2560 * 2;
  const size_t ACT_B = (size_t)92280832;
  auto aln = [](size_t v) { return (v + 255) & ~(size_t)255; };
  const bool big = ws_size >= aln(WT_BIG) + aln(TAB_B) + aln(H_B) + aln(ACT_B);

  char* ws = (char*)d_ws;
  size_t off = 0;
  auto alloc = [&](size_t bytes) {
    char* p = ws + off;
    off += (bytes + 255) & ~(size_t)255;
    return p;
  };
  f16* wT    = (f16*)alloc(big ? WT_BIG : WT_SMALL);
  float* tab = (float*)alloc(TAB_B);
  f16* h     = (f16*)alloc(H_B);
  char* act  = alloc(ACT_B);
  // attention-phase overlays inside act:
  f16* qkv    = (f16*)(act);                                    // 33.5 MB
  f16* q_g    = (f16*)(act + (size_t)33554432);                 // 16.8 MB
  f16* k_g    = (f16*)(act + (size_t)33554432 + 16777216);      //  8.4 MB
  f16* v_n    = (f16*)(act + (size_t)33554432 + 16777216 + 8388608);
  f16* vtb    = (f16*)(act + (size_t)33554432 + 16777216 + 2 * 8388608);
  f16* ctx    = (f16*)(act + (size_t)33554432 + 16777216 + 3 * 8388608);
  f16* attn_o = (f16*)(act);            // reuse qkv slot (dead after norm_rope)
  // ffw-phase overlays:
  f16* gbuf = (f16*)(act);              // 83.9 MB spans whole act region
  f16* ffw  = h;                        // h dead after it's consumed as GEMM A
  f16* wuT  = wT + (size_t)10240 * 2560;  // big path only
  (void)in_sizes; (void)n_in; (void)out_size;

  dim3 tb(32, 8);
  rope_table_k<<<1024, 256, 0, stream>>>(tab);

  // ---- attention path ----
  rmsnorm_f32_f16<<<4096, 256, 0, stream>>>(x, pre_attn, h);
  // wq|wk|wv -> wT as [4096][2560] (q rows 0-2047, k 2048-3071, v 3072-4095)
  transpose_w<<<dim3(2048 / 32, 2560 / 32), tb, 0, stream>>>(wq, wT, 2560, 2048);
  transpose_w<<<dim3(1024 / 32, 2560 / 32), tb, 0, stream>>>(wk, wT + (size_t)2048 * 2560, 2560, 1024);
  transpose_w<<<dim3(1024 / 32, 2560 / 32), tb, 0, stream>>>(wv, wT + (size_t)3072 * 2560, 2560, 1024);
  gemm256<0><<<dim3(4096 / 256, 4096 / 256), 512, 131072, stream>>>(h, wT, qkv, nullptr, 4096, 4096, 2560);
  norm_rope_k<<<4096, 256, 0, stream>>>(qkv, positions, q_scale, k_scale, tab, q_g, k_g, v_n);
  transpose_v_k<<<dim3(2048 / 32, 256 / 32, 8), tb, 0, stream>>>(v_n, vtb);
  flash_attn_k<<<dim3(32, 8, 2), 256, 0, stream>>>(q_g, k_g, vtb, ctx);
  transpose_w<<<dim3(2560 / 32, 2048 / 32), tb, 0, stream>>>(wo, wT, 2048, 2560);
  gemm256<0><<<dim3(2560 / 256, 4096 / 256), 512, 131072, stream>>>(ctx, wT, attn_o, nullptr, 4096, 2560, 2048);
  residual_rmsnorm<<<4096, 256, 0, stream>>>(x, attn_o, post_attn, out);

  // ---- ffw path ----
  rmsnorm_f32_f16<<<4096, 256, 0, stream>>>(out, pre_ffw, h);
  if (big) {
    // fused gate+up: grid 80x16 = 1280 blocks; round-locality decode inside
    transpose_w<<<dim3(10240 / 32, 2560 / 32), tb, 0, stream>>>(w_gate, wT, 2560, 10240);
    transpose_w<<<dim3(10240 / 32, 2560 / 32), tb, 0, stream>>>(w_up, wuT, 2560, 10240);
    gemm256<3><<<dim3(80, 16), 512, 131072, stream>>>(h, wT, gbuf, wuT, 4096, 10240, 2560);
  } else {
    transpose_w<<<dim3(10240 / 32, 2560 / 32), tb, 0, stream>>>(w_gate, wT, 2560, 10240);
    gemm256<1><<<dim3(10240 / 256, 4096 / 256), 512, 131072, stream>>>(h, wT, gbuf, nullptr, 4096, 10240, 2560);
    transpose_w<<<dim3(10240 / 32, 2560 / 32), tb, 0, stream>>>(w_up, wT, 2560, 10240);
    gemm256<2><<<dim3(10240 / 256, 4096 / 256), 512, 131072, stream>>>(h, wT, gbuf, gbuf, 4096, 10240, 2560);
  }
  transpose_w<<<dim3(2560 / 32, 10240 / 32), tb, 0, stream>>>(w_down, wT, 10240, 2560);
  gemm256<0><<<dim3(2560 / 256, 4096 / 256), 512, 131072, stream>>>(gbuf, wT, ffw, nullptr, 4096, 2560, 10240);
  residual_rmsnorm<<<4096, 256, 0, stream>>>(out, ffw, post_ffw, out);
}